// Round 18
// baseline (306.316 us; speedup 1.0000x reference)
//
#include <hip/hip_runtime.h>
#include <stdint.h>

#define AS1 __attribute__((address_space(1)))
#define AS3 __attribute__((address_space(3)))

typedef __bf16 bf16x8 __attribute__((ext_vector_type(8)));
typedef float  f32x4  __attribute__((ext_vector_type(4)));

// ---------------------------------------------------------------- fused setup (unchanged, R14-verified)
__global__ __launch_bounds__(256) void prep_all(
    const float* __restrict__ value, __bf16* __restrict__ vbf,
    const float* __restrict__ Wv,    __bf16* __restrict__ wvbf,
    const float* __restrict__ q,     const float* __restrict__ Wq,
    const float* __restrict__ bias,  const float* __restrict__ convb,
    float* __restrict__ qb2,         float* __restrict__ ctx)
{
    const int bid = blockIdx.x, tid = threadIdx.x;
    if (bid < 32768) {
        int i = bid * 256 + tid;
        const float4* p = (const float4*)value + (size_t)i * 2;
        float4 x = p[0], y = p[1];
        bf16x8 v;
        v[0] = (__bf16)x.x; v[1] = (__bf16)x.y; v[2] = (__bf16)x.z; v[3] = (__bf16)x.w;
        v[4] = (__bf16)y.x; v[5] = (__bf16)y.y; v[6] = (__bf16)y.z; v[7] = (__bf16)y.w;
        *((bf16x8*)vbf + i) = v;
    } else if (bid < 33280) {
        int i = (bid - 32768) * 256 + tid;
        const float4* p = (const float4*)Wv + (size_t)i * 2;
        float4 x = p[0], y = p[1];
        bf16x8 v;
        v[0] = (__bf16)x.x; v[1] = (__bf16)x.y; v[2] = (__bf16)x.z; v[3] = (__bf16)x.w;
        v[4] = (__bf16)y.x; v[5] = (__bf16)y.y; v[6] = (__bf16)y.z; v[7] = (__bf16)y.w;
        *((bf16x8*)wvbf + i) = v;
        if (i < 4096) {
            float4 z = {0.f, 0.f, 0.f, 0.f};
            ((float4*)ctx)[i * 2]     = z;
            ((float4*)ctx)[i * 2 + 1] = z;
        }
    } else {
        int wid  = tid >> 6;
        int lane = tid & 63;
        int a    = (bid - 33280) * 4 + wid;
        const float* wr_ = Wq + (size_t)a * 1024;
        float w[16];
#pragma unroll
        for (int j = 0; j < 16; ++j) w[j] = wr_[lane + 64 * j];
        float bb = bias[a] + convb[a];
        for (int b = 0; b < 32; ++b) {
            const float* qr = q + (size_t)b * 1024;
            float s = 0.f;
#pragma unroll
            for (int j = 0; j < 16; ++j) s += w[j] * qr[lane + 64 * j];
            for (int m = 1; m < 64; m <<= 1) s += __shfl_xor(s, m);
            if (lane == 0) qb2[b * 1024 + a] = s + bb;
        }
    }
}

// ---------------------------------------------------------------- 8-phase 256² GEMM, R17 race-fixed
// 256x256, BK=64, 8 waves (2Mx4N), 128 KB LDS. Raw s_barrier only; counted vmcnt(6)
// per K-tile (vmcnt(0) at last tile — tail fix). Staging "halves" now EXACTLY match
// the phase-consumed regions (R16's bug: [0,128) halves vs interleaved reads):
//   A half h = rows (r>>6)*128 + h*64 + (r&63)   -> ph1 reads h0, ph3 reads h1
//   B half h = rows (r>>5)*64  + h*32 + (r&31)   -> ph1 reads h0 (bF0), ph2 reads h1 (bF1)
// sigma-staging: ph1 -> A-h1(T+1) into buf^1; ph2/3/4 -> A-h0/B-h0/B-h1(T+2) into buf,
// each overwriting a region whose reads finished one phase earlier (operands reg-cached).
__global__ __launch_bounds__(512, 2) void gemm_fused(
    const __bf16* __restrict__ Abf,   // [65536][1024] bf16 value
    const __bf16* __restrict__ Bbf,   // [1024][1024] bf16 Wv
    const float*  __restrict__ qb2,   // [32][1024]
    const float*  __restrict__ la,    // [32][2048]
    const float*  __restrict__ convw, // [1024][3]
    const float*  __restrict__ fcw,   // [1024]
    float* __restrict__ ep)           // [4][32][2048] partial energies per col-tile
{
    constexpr int K = 1024, NT = 16;
    __shared__ __bf16 As[2][256 * 64];   // 32 KB each buf
    __shared__ __bf16 Bs[2][256 * 64];

    const int tid  = threadIdx.x;
    const int lane = tid & 63;
    const int wid  = tid >> 6;
    const int wr   = wid >> 2, wc = wid & 3;     // 2 x 4 waves, each owns 128x64

    const int bid = blockIdx.x;                  // nwg = 1024, %8 == 0 (T1)
    const int swz = (bid & 7) * 128 + (bid >> 3);
    const int rt  = swz >> 2;                    // 0..255
    const int ct  = swz & 3;                     // 0..3
    const int rowBase = rt * 256;
    const int colBase = ct * 256;

    f32x4 acc[8][4] = {};

    // stage one half (2 gload_lds/thread). LDS dest linear; row&7 == r&7 so the
    // pre-swizzled source chunk (idx^r)&7 pairs with read slot k^(row&7) (rule #21).
    auto STAGE_A = [&](int buf, int h, int T) {
        const int k0 = T * 64;
#pragma unroll
        for (int rr = 0; rr < 2; ++rr) {
            int idx = rr * 512 + tid;            // 0..1023 within half
            int r   = idx >> 3;                  // 0..127
            int row = ((r >> 6) * 128) + h * 64 + (r & 63);   // interleaved quarter rows
            int ssw = (idx ^ r) & 7;
            const __bf16* g = Abf + (size_t)(rowBase + row) * K + k0 + ssw * 8;
            __builtin_amdgcn_global_load_lds((AS1 void*)g,
                (AS3 void*)(&As[buf][row * 64 + (idx & 7) * 8]), 16, 0, 0);
        }
    };
    auto STAGE_B = [&](int buf, int h, int T) {
        const int k0 = T * 64;
#pragma unroll
        for (int rr = 0; rr < 2; ++rr) {
            int idx = rr * 512 + tid;
            int r   = idx >> 3;
            int row = ((r >> 5) * 64) + h * 32 + (r & 31);    // interleaved 32-row stripes
            int ssw = (idx ^ r) & 7;
            const __bf16* g = Bbf + (size_t)(colBase + row) * K + k0 + ssw * 8;
            __builtin_amdgcn_global_load_lds((AS1 void*)g,
                (AS3 void*)(&Bs[buf][row * 64 + (idx & 7) * 8]), 16, 0, 0);
        }
    };

    // -------- prologue: tile0 all 4 halves + tile1 {A-h0, B-h0, B-h1} (14 loads/thread·2)
    STAGE_A(0, 0, 0); STAGE_A(0, 1, 0); STAGE_B(0, 0, 0); STAGE_B(0, 1, 0);
    STAGE_A(1, 0, 1); STAGE_B(1, 0, 1); STAGE_B(1, 1, 1);
    asm volatile("s_waitcnt vmcnt(6)" ::: "memory");   // tile0's 8 landed; 6 in flight
    __builtin_amdgcn_s_barrier();

#pragma unroll 1
    for (int T = 0; T < NT; ++T) {
        const int buf = T & 1;
        bf16x8 aF[4][2], bF0[2][2], bF1[2][2];

        if (T + 1 == NT) {                       // tail: only 8 in flight -> full drain
            asm volatile("s_waitcnt vmcnt(0)" ::: "memory");
            __builtin_amdgcn_s_barrier();
        } else if (T > 0) {                      // steady state: 14 in flight -> drain 8
            asm volatile("s_waitcnt vmcnt(6)" ::: "memory");
            __builtin_amdgcn_s_barrier();
        }

        // ---- ph1: read A-h0 + B-h0; stage A-h1(T+1) -> buf^1; MFMA Q(A0,B0)
#pragma unroll
        for (int mi = 0; mi < 4; ++mi)
#pragma unroll
            for (int kk = 0; kk < 2; ++kk) {
                int row  = wr * 128 + mi * 16 + (lane & 15);
                int slot = (kk * 4 + (lane >> 4)) ^ (row & 7);
                aF[mi][kk] = *(const bf16x8*)(&As[buf][row * 64 + slot * 8]);
            }
#pragma unroll
        for (int ni = 0; ni < 2; ++ni)
#pragma unroll
            for (int kk = 0; kk < 2; ++kk) {
                int row  = wc * 64 + ni * 16 + (lane & 15);
                int slot = (kk * 4 + (lane >> 4)) ^ (row & 7);
                bF0[ni][kk] = *(const bf16x8*)(&Bs[buf][row * 64 + slot * 8]);
            }
        if (T < NT - 1) STAGE_A(buf ^ 1, 1, T + 1);
        __builtin_amdgcn_s_barrier();
        __builtin_amdgcn_s_setprio(1);
#pragma unroll
        for (int mi = 0; mi < 4; ++mi)
#pragma unroll
            for (int ni = 0; ni < 2; ++ni)
#pragma unroll
                for (int kk = 0; kk < 2; ++kk)
                    acc[mi][ni] = __builtin_amdgcn_mfma_f32_16x16x32_bf16(
                        aF[mi][kk], bF0[ni][kk], acc[mi][ni], 0, 0, 0);
        __builtin_amdgcn_s_setprio(0);
        __builtin_amdgcn_s_barrier();

        // ---- ph2: read B-h1; stage A-h0(T+2) -> buf (region consumed in ph1); Q(A0,B1)
#pragma unroll
        for (int ni = 0; ni < 2; ++ni)
#pragma unroll
            for (int kk = 0; kk < 2; ++kk) {
                int row  = wc * 64 + (2 + ni) * 16 + (lane & 15);
                int slot = (kk * 4 + (lane >> 4)) ^ (row & 7);
                bF1[ni][kk] = *(const bf16x8*)(&Bs[buf][row * 64 + slot * 8]);
            }
        if (T < NT - 2) STAGE_A(buf, 0, T + 2);
        __builtin_amdgcn_s_barrier();
        __builtin_amdgcn_s_setprio(1);
#pragma unroll
        for (int mi = 0; mi < 4; ++mi)
#pragma unroll
            for (int ni = 0; ni < 2; ++ni)
#pragma unroll
                for (int kk = 0; kk < 2; ++kk)
                    acc[mi][2 + ni] = __builtin_amdgcn_mfma_f32_16x16x32_bf16(
                        aF[mi][kk], bF1[ni][kk], acc[mi][2 + ni], 0, 0, 0);
        __builtin_amdgcn_s_setprio(0);
        __builtin_amdgcn_s_barrier();

        // ---- ph3: read A-h1 (overwrite aF); stage B-h0(T+2) -> buf (consumed in ph1); Q(A1,B0)
#pragma unroll
        for (int mi = 0; mi < 4; ++mi)
#pragma unroll
            for (int kk = 0; kk < 2; ++kk) {
                int row  = wr * 128 + (4 + mi) * 16 + (lane & 15);
                int slot = (kk * 4 + (lane >> 4)) ^ (row & 7);
                aF[mi][kk] = *(const bf16x8*)(&As[buf][row * 64 + slot * 8]);
            }
        if (T < NT - 2) STAGE_B(buf, 0, T + 2);
        __builtin_amdgcn_s_barrier();
        __builtin_amdgcn_s_setprio(1);
#pragma unroll
        for (int mi = 0; mi < 4; ++mi)
#pragma unroll
            for (int ni = 0; ni < 2; ++ni)
#pragma unroll
                for (int kk = 0; kk < 2; ++kk)
                    acc[4 + mi][ni] = __builtin_amdgcn_mfma_f32_16x16x32_bf16(
                        aF[mi][kk], bF0[ni][kk], acc[4 + mi][ni], 0, 0, 0);
        __builtin_amdgcn_s_setprio(0);
        __builtin_amdgcn_s_barrier();

        // ---- ph4: stage B-h1(T+2) -> buf (consumed in ph2); Q(A1,B1)
        if (T < NT - 2) STAGE_B(buf, 1, T + 2);
        __builtin_amdgcn_s_barrier();
        __builtin_amdgcn_s_setprio(1);
#pragma unroll
        for (int mi = 0; mi < 4; ++mi)
#pragma unroll
            for (int ni = 0; ni < 2; ++ni)
#pragma unroll
                for (int kk = 0; kk < 2; ++kk)
                    acc[4 + mi][2 + ni] = __builtin_amdgcn_mfma_f32_16x16x32_bf16(
                        aF[mi][kk], bF1[ni][kk], acc[4 + mi][2 + ni], 0, 0, 0);
        __builtin_amdgcn_s_setprio(0);
        __builtin_amdgcn_s_barrier();
    }

    // -------- fused epilogue (R6-verified layout) --------
    __syncthreads();
    const int b     = rowBase >> 11;            // uniform: 2048 % 256 == 0
    const int tTile = rowBase & 2047;
    const float* lab  = la  + (size_t)b * 2048;
    const float* qrow = qb2 + (size_t)b * 1024;

    float cw0[4], cw1[4], cw2[4], fv[4], qv[4];
#pragma unroll
    for (int ni = 0; ni < 4; ++ni) {
        int a = colBase + wc * 64 + ni * 16 + (lane & 15);
        cw0[ni] = convw[a * 3 + 0];
        cw1[ni] = convw[a * 3 + 1];
        cw2[ni] = convw[a * 3 + 2];
        fv[ni]  = fcw[a];
        qv[ni]  = qrow[a];
    }
    float* eps = (float*)&As[0][0];             // [256][4] overlay; As dead
    const int g4 = (lane >> 4) * 4;
#pragma unroll
    for (int mi = 0; mi < 8; ++mi) {
#pragma unroll
        for (int j = 0; j < 4; ++j) {
            int rloc = wr * 128 + mi * 16 + g4 + j;       // 0..255
            int t = tTile + rloc;
            float p1 = lab[t];
            float p0 = (t > 0)    ? lab[t - 1] : 0.f;     // SAME pad, per-b boundaries
            float p2 = (t < 2047) ? lab[t + 1] : 0.f;
            float sum = 0.f;
#pragma unroll
            for (int ni = 0; ni < 4; ++ni) {
                float e = acc[mi][ni][j] + qv[ni] + cw0[ni] * p0 + cw1[ni] * p1 + cw2[ni] * p2;
                float h = 1.f - 2.f / (1.f + __expf(2.f * e));   // tanh
                sum += fv[ni] * h;
            }
            sum += __shfl_xor(sum, 1);
            sum += __shfl_xor(sum, 2);
            sum += __shfl_xor(sum, 4);
            sum += __shfl_xor(sum, 8);
            if ((lane & 15) == 0) eps[rloc * 4 + wc] = sum;
        }
    }
    __syncthreads();
    if (tid < 256) {
        float e = eps[tid * 4 + 0] + eps[tid * 4 + 1] + eps[tid * 4 + 2] + eps[tid * 4 + 3];
        ep[(size_t)ct * 65536 + rowBase + tid] = e;
    }
}

// ---------------------------------------------------------------- fused softmax + context (4 partials)
__global__ __launch_bounds__(256) void context_softmax(const float* __restrict__ ep,
                                                       const __bf16* __restrict__ vbf,
                                                       float* __restrict__ attn,
                                                       float* __restrict__ ctx) {
    int b = blockIdx.x, tc = blockIdx.y, tid = threadIdx.x;
    __shared__ float e[2048];
    __shared__ float red[4], red2[4];

    float e8[8];
    float m = -1e30f;
#pragma unroll
    for (int k = 0; k < 8; ++k) {
        int t = tid + 256 * k;
        float s = 0.f;
#pragma unroll
        for (int ct = 0; ct < 4; ++ct) s += ep[(size_t)ct * 65536 + b * 2048 + t];
        e8[k] = s;
        m = fmaxf(m, s);
    }
    for (int s = 1; s < 64; s <<= 1) m = fmaxf(m, __shfl_xor(m, s));
    if ((tid & 63) == 0) red[tid >> 6] = m;
    __syncthreads();
    m = fmaxf(fmaxf(red[0], red[1]), fmaxf(red[2], red[3]));

    float s = 0.f, vals[8];
#pragma unroll
    for (int k = 0; k < 8; ++k) {
        vals[k] = __expf(e8[k] - m);
        s += vals[k];
        e[tid + 256 * k] = vals[k];
    }
    for (int t2 = 1; t2 < 64; t2 <<= 1) s += __shfl_xor(s, t2);
    if ((tid & 63) == 0) red2[tid >> 6] = s;
    __syncthreads();
    s = red2[0] + red2[1] + red2[2] + red2[3];
    float inv = 1.f / s;

    if (tc == 0) {
#pragma unroll
        for (int k = 0; k < 8; ++k)
            attn[(size_t)b * 2048 + tid + 256 * k] = vals[k] * inv;
    }

    int half = tid >> 7, dc = tid & 127;
    int t0 = tc * 256 + half * 128;
    const float*  wv_ = &e[t0];
    const __bf16* vb  = vbf + ((size_t)(b * 2048 + t0)) * 1024 + dc * 8;
    float c[8] = {};
#pragma unroll 4
    for (int t = 0; t < 128; ++t) {
        float  w = wv_[t] * inv;
        bf16x8 v = *(const bf16x8*)(vb + (size_t)t * 1024);
#pragma unroll
        for (int k = 0; k < 8; ++k) c[k] += w * (float)v[k];
    }
    float* out = ctx + (size_t)b * 1024 + dc * 8;
#pragma unroll
    for (int k = 0; k < 8; ++k) atomicAdd(out + k, c[k]);
}

// ================================================================ host
extern "C" void kernel_launch(void* const* d_in, const int* in_sizes, int n_in,
                              void* d_out, int out_size, void* d_ws, size_t ws_size,
                              hipStream_t stream) {
    const float* query     = (const float*)d_in[0];
    const float* value     = (const float*)d_in[1];
    const float* last_attn = (const float*)d_in[2];
    const float* conv_w    = (const float*)d_in[3];
    const float* conv_b    = (const float*)d_in[4];
    const float* Wq        = (const float*)d_in[5];
    const float* Wv        = (const float*)d_in[6];
    const float* bias      = (const float*)d_in[7];
    const float* fc_w      = (const float*)d_in[8];
    // fc_b (d_in[9]) cancels in softmax

    float* ctx  = (float*)d_out;             // [32][1024]
    float* attn = (float*)d_out + 32 * 1024; // [32][2048]

    const size_t VBF_B  = (size_t)65536 * 1024 * 2;  // 128 MB
    const size_t WVBF_B = (size_t)1024 * 1024 * 2;   //   2 MB
    const size_t QB2_B  = (size_t)32 * 1024 * 4;     // 128 KB
    const size_t EP_B   = (size_t)4 * 32 * 2048 * 4; //   1 MB
    if (ws_size < VBF_B + WVBF_B + QB2_B + EP_B) return;

    char*   ws   = (char*)d_ws;
    __bf16* vbf  = (__bf16*)ws;
    __bf16* wvbf = (__bf16*)(ws + VBF_B);
    float*  qb2  = (float*)(ws + VBF_B + WVBF_B);
    float*  ep   = (float*)(ws + VBF_B + WVBF_B + QB2_B);

    prep_all<<<33536, 256, 0, stream>>>(value, vbf, Wv, wvbf,
                                        query, Wq, bias, conv_b, qb2, ctx);

    gemm_fused<<<1024, 512, 0, stream>>>(vbf, wvbf, qb2, last_attn, conv_w, fc_w, ep);

    dim3 gc(32, 8);
    context_softmax<<<gc, 256, 0, stream>>>(ep, vbf, attn, ctx);
}

// Round 19
// 294.635 us; speedup vs baseline: 1.0396x; 1.0396x over previous
//
#include <hip/hip_runtime.h>
#include <stdint.h>

#define AS1 __attribute__((address_space(1)))
#define AS3 __attribute__((address_space(3)))

typedef __bf16 bf16x8 __attribute__((ext_vector_type(8)));
typedef float  f32x4  __attribute__((ext_vector_type(4)));

// ---------------------------------------------------------------- fused setup:
// [0, 32768)        : cast value f32->bf16 (8 elems/thread)
// [32768, 33280)    : cast Wv f32->bf16 (+ first 16 blocks zero ctx)
// [33280, 33536)    : qb2[b][a] = q[b]·Wq[a] + bias[a] + conv_b[a]
__global__ __launch_bounds__(256) void prep_all(
    const float* __restrict__ value, __bf16* __restrict__ vbf,
    const float* __restrict__ Wv,    __bf16* __restrict__ wvbf,
    const float* __restrict__ q,     const float* __restrict__ Wq,
    const float* __restrict__ bias,  const float* __restrict__ convb,
    float* __restrict__ qb2,         float* __restrict__ ctx)
{
    const int bid = blockIdx.x, tid = threadIdx.x;
    if (bid < 32768) {                       // value cast: 8M bf16x8 items
        int i = bid * 256 + tid;
        const float4* p = (const float4*)value + (size_t)i * 2;
        float4 x = p[0], y = p[1];
        bf16x8 v;
        v[0] = (__bf16)x.x; v[1] = (__bf16)x.y; v[2] = (__bf16)x.z; v[3] = (__bf16)x.w;
        v[4] = (__bf16)y.x; v[5] = (__bf16)y.y; v[6] = (__bf16)y.z; v[7] = (__bf16)y.w;
        *((bf16x8*)vbf + i) = v;
    } else if (bid < 33280) {                // Wv cast: 131072 items
        int i = (bid - 32768) * 256 + tid;
        const float4* p = (const float4*)Wv + (size_t)i * 2;
        float4 x = p[0], y = p[1];
        bf16x8 v;
        v[0] = (__bf16)x.x; v[1] = (__bf16)x.y; v[2] = (__bf16)x.z; v[3] = (__bf16)x.w;
        v[4] = (__bf16)y.x; v[5] = (__bf16)y.y; v[6] = (__bf16)y.z; v[7] = (__bf16)y.w;
        *((bf16x8*)wvbf + i) = v;
        if (i < 4096) {                      // zero ctx: 32768 floats = 8192 float4
            float4 z = {0.f, 0.f, 0.f, 0.f};
            ((float4*)ctx)[i * 2]     = z;
            ((float4*)ctx)[i * 2 + 1] = z;
        }
    } else {                                 // qb2 prep: 256 blocks x 4 waves
        int wid  = tid >> 6;
        int lane = tid & 63;
        int a    = (bid - 33280) * 4 + wid;
        const float* wr_ = Wq + (size_t)a * 1024;
        float w[16];
#pragma unroll
        for (int j = 0; j < 16; ++j) w[j] = wr_[lane + 64 * j];
        float bb = bias[a] + convb[a];
        for (int b = 0; b < 32; ++b) {
            const float* qr = q + (size_t)b * 1024;
            float s = 0.f;
#pragma unroll
            for (int j = 0; j < 16; ++j) s += w[j] * qr[lane + 64 * j];
            for (int m = 1; m < 64; m <<= 1) s += __shfl_xor(s, m);
            if (lane == 0) qb2[b * 1024 + a] = s + bb;
        }
    }
}

// ---------------------------------------------------------------- fused GEMM + loc-conv + tanh + fc reduce
// FINAL operating point (723 TF, empirically optimal across the mapped neighborhood):
// 128x128 tile, BK=64, 4 waves (2x2), SINGLE-buffered 32 KB LDS, __launch_bounds__(256,4)
// -> 60 VGPR + 64 AGPR = 124 regs, 4 blocks/CU. Inter-block TLP (m114) provides the
// stage/compute overlap; every structural neighbor measured worse:
//   BK=32 dbuf 215us (R14) | BK=64 dbuf-66KB 274us (R5-class) | 256² 2ph 228us (R6)
//   256² 8ph counted-vmcnt 199us (R17, race-free) | (256,5) cap: acc spills, 379us (R10)
// T1 chunked XCD swizzle (FETCH 535->85 MB) + T2 XOR swizzle (conflicts 5e7->0).
__global__ __launch_bounds__(256, 4) void gemm_fused(
    const __bf16* __restrict__ Abf,   // [65536][1024] bf16 value
    const __bf16* __restrict__ Bbf,   // [1024][1024] bf16 Wv
    const float*  __restrict__ qb2,   // [32][1024]
    const float*  __restrict__ la,    // [32][2048]
    const float*  __restrict__ convw, // [1024][3]
    const float*  __restrict__ fcw,   // [1024]
    float* __restrict__ ep)           // [8][32][2048] partial energies per col-tile
{
    constexpr int K = 1024, NT = 16;
    __shared__ __bf16 As[128 * 64];   // 16 KB (reused as epilogue scratch)
    __shared__ __bf16 Bs[128 * 64];   // 16 KB -> total 32768 B

    const int tid  = threadIdx.x;
    const int lane = tid & 63;
    const int wid  = tid >> 6;
    const int wr   = wid >> 1, wc = wid & 1;

    const int bid = blockIdx.x;                       // nwg = 4096, %8 == 0
    const int swz = (bid & 7) * 512 + (bid >> 3);
    const int rt  = swz >> 3;                         // row tile 0..511
    const int ct  = swz & 7;                          // col tile 0..7
    const int rowBase = rt * 128;
    const int colBase = ct * 128;

    f32x4 acc[4][4] = {};

#pragma unroll 1
    for (int t = 0; t < NT; ++t) {
        const int k0 = t * 64;
        // stage: LDS dest linear (gload_lds), global 16B-chunk source swizzled s^(r&7)
#pragma unroll
        for (int is = 0; is < 4; ++is) {
            int idx16 = is * 256 + tid;               // 0..1023
            int r     = idx16 >> 3;                   // row 0..127
            int ssw   = (idx16 ^ r) & 7;
            const __bf16* ga = Abf + (size_t)(rowBase + r) * K + k0 + ssw * 8;
            __builtin_amdgcn_global_load_lds((AS1 void*)ga, (AS3 void*)(&As[idx16 * 8]), 16, 0, 0);
            const __bf16* gb = Bbf + (size_t)(colBase + r) * K + k0 + ssw * 8;
            __builtin_amdgcn_global_load_lds((AS1 void*)gb, (AS3 void*)(&Bs[idx16 * 8]), 16, 0, 0);
        }
        __syncthreads();                              // drains vmcnt for gload_lds
#pragma unroll
        for (int kk = 0; kk < 2; ++kk) {
            bf16x8 af[4], bfr[4];
#pragma unroll
            for (int mi = 0; mi < 4; ++mi) {
                int row  = wr * 64 + mi * 16 + (lane & 15);
                int slot = (kk * 4 + (lane >> 4)) ^ (row & 7);
                af[mi] = *(const bf16x8*)(&As[row * 64 + slot * 8]);
            }
#pragma unroll
            for (int ni = 0; ni < 4; ++ni) {
                int row  = wc * 64 + ni * 16 + (lane & 15);
                int slot = (kk * 4 + (lane >> 4)) ^ (row & 7);
                bfr[ni] = *(const bf16x8*)(&Bs[row * 64 + slot * 8]);
            }
#pragma unroll
            for (int mi = 0; mi < 4; ++mi)
#pragma unroll
                for (int ni = 0; ni < 4; ++ni)
                    acc[mi][ni] = __builtin_amdgcn_mfma_f32_16x16x32_bf16(
                        af[mi], bfr[ni], acc[mi][ni], 0, 0, 0);
        }
        __syncthreads();                              // buffer reuse fence
    }

    // -------- fused epilogue --------
    const int b     = rowBase >> 11;            // uniform: 2048 % 128 == 0
    const int tTile = rowBase & 2047;
    const float* lab  = la  + (size_t)b * 2048;
    const float* qrow = qb2 + (size_t)b * 1024;

    float cw0[4], cw1[4], cw2[4], fv[4], qv[4];
#pragma unroll
    for (int ni = 0; ni < 4; ++ni) {
        int a = colBase + wc * 64 + ni * 16 + (lane & 15);
        cw0[ni] = convw[a * 3 + 0];
        cw1[ni] = convw[a * 3 + 1];
        cw2[ni] = convw[a * 3 + 2];
        fv[ni]  = fcw[a];
        qv[ni]  = qrow[a];
    }
    float* eps = (float*)&As[0];                // [128][2] overlay; As dead after K-loop
    const int g4 = (lane >> 4) * 4;
#pragma unroll
    for (int mi = 0; mi < 4; ++mi) {
#pragma unroll
        for (int j = 0; j < 4; ++j) {
            int rloc = wr * 64 + mi * 16 + g4 + j;        // 0..127 within tile
            int t = tTile + rloc;                          // t within this b
            float p1 = lab[t];
            float p0 = (t > 0)    ? lab[t - 1] : 0.f;     // SAME pad, per-b boundaries
            float p2 = (t < 2047) ? lab[t + 1] : 0.f;
            float sum = 0.f;
#pragma unroll
            for (int ni = 0; ni < 4; ++ni) {
                float e = acc[mi][ni][j] + qv[ni] + cw0[ni] * p0 + cw1[ni] * p1 + cw2[ni] * p2;
                float h = 1.f - 2.f / (1.f + __expf(2.f * e));   // tanh
                sum += fv[ni] * h;
            }
            sum += __shfl_xor(sum, 1);
            sum += __shfl_xor(sum, 2);
            sum += __shfl_xor(sum, 4);
            sum += __shfl_xor(sum, 8);
            if ((lane & 15) == 0)
                eps[rloc * 2 + wc] = sum;
        }
    }
    __syncthreads();
    if (tid < 128) {
        float e = eps[tid * 2 + 0] + eps[tid * 2 + 1];
        ep[(size_t)ct * 65536 + rowBase + tid] = e;   // rowBase+tid == b*2048 + t
    }
}

// ---------------------------------------------------------------- fused softmax + context
// grid (32, 8): each block rebuilds its b's full softmax from ep (8 partials x 2048,
// 64 KB L2-hot reads), then computes its 256-t slice of context. tc==0 writes attn.
__global__ __launch_bounds__(256) void context_softmax(const float* __restrict__ ep,
                                                       const __bf16* __restrict__ vbf,
                                                       float* __restrict__ attn,
                                                       float* __restrict__ ctx) {
    int b = blockIdx.x, tc = blockIdx.y, tid = threadIdx.x;
    __shared__ float e[2048];
    __shared__ float red[4], red2[4];

    float e8[8];
    float m = -1e30f;
#pragma unroll
    for (int k = 0; k < 8; ++k) {
        int t = tid + 256 * k;
        float s = 0.f;
#pragma unroll
        for (int ct = 0; ct < 8; ++ct) s += ep[(size_t)ct * 65536 + b * 2048 + t];
        e8[k] = s;
        m = fmaxf(m, s);
    }
    for (int s = 1; s < 64; s <<= 1) m = fmaxf(m, __shfl_xor(m, s));
    if ((tid & 63) == 0) red[tid >> 6] = m;
    __syncthreads();
    m = fmaxf(fmaxf(red[0], red[1]), fmaxf(red[2], red[3]));

    float s = 0.f, vals[8];
#pragma unroll
    for (int k = 0; k < 8; ++k) {
        vals[k] = __expf(e8[k] - m);
        s += vals[k];
        e[tid + 256 * k] = vals[k];          // unnormalized weights into LDS
    }
    for (int t2 = 1; t2 < 64; t2 <<= 1) s += __shfl_xor(s, t2);
    if ((tid & 63) == 0) red2[tid >> 6] = s;
    __syncthreads();                          // also fences the e[] writes for PV
    s = red2[0] + red2[1] + red2[2] + red2[3];
    float inv = 1.f / s;

    if (tc == 0) {
#pragma unroll
        for (int k = 0; k < 8; ++k)
            attn[(size_t)b * 2048 + tid + 256 * k] = vals[k] * inv;
    }

    // PV: this block covers t in [tc*256, tc*256+256)
    int half = tid >> 7, dc = tid & 127;
    int t0 = tc * 256 + half * 128;
    const float*  wv_ = &e[t0];
    const __bf16* vb  = vbf + ((size_t)(b * 2048 + t0)) * 1024 + dc * 8;
    float c[8] = {};
#pragma unroll 4
    for (int t = 0; t < 128; ++t) {
        float  w = wv_[t] * inv;
        bf16x8 v = *(const bf16x8*)(vb + (size_t)t * 1024);
#pragma unroll
        for (int k = 0; k < 8; ++k) c[k] += w * (float)v[k];
    }
    float* out = ctx + (size_t)b * 1024 + dc * 8;
#pragma unroll
    for (int k = 0; k < 8; ++k) atomicAdd(out + k, c[k]);
}

// ================================================================ host
extern "C" void kernel_launch(void* const* d_in, const int* in_sizes, int n_in,
                              void* d_out, int out_size, void* d_ws, size_t ws_size,
                              hipStream_t stream) {
    const float* query     = (const float*)d_in[0];
    const float* value     = (const float*)d_in[1];
    const float* last_attn = (const float*)d_in[2];
    const float* conv_w    = (const float*)d_in[3];
    const float* conv_b    = (const float*)d_in[4];
    const float* Wq        = (const float*)d_in[5];
    const float* Wv        = (const float*)d_in[6];
    const float* bias      = (const float*)d_in[7];
    const float* fc_w      = (const float*)d_in[8];
    // fc_b (d_in[9]) cancels in softmax

    float* ctx  = (float*)d_out;             // [32][1024]
    float* attn = (float*)d_out + 32 * 1024; // [32][2048]

    const size_t VBF_B  = (size_t)65536 * 1024 * 2;  // 128 MB full value in bf16
    const size_t WVBF_B = (size_t)1024 * 1024 * 2;   //   2 MB
    const size_t QB2_B  = (size_t)32 * 1024 * 4;     // 128 KB
    const size_t EP_B   = (size_t)8 * 32 * 2048 * 4; //   2 MB
    if (ws_size < VBF_B + WVBF_B + QB2_B + EP_B) return;

    char*   ws   = (char*)d_ws;
    __bf16* vbf  = (__bf16*)ws;
    __bf16* wvbf = (__bf16*)(ws + VBF_B);
    float*  qb2  = (float*)(ws + VBF_B + WVBF_B);
    float*  ep   = (float*)(ws + VBF_B + WVBF_B + QB2_B);

    // 1) all setup in one launch: value cast + Wv cast + ctx zero + qb2
    prep_all<<<33536, 256, 0, stream>>>(value, vbf, Wv, wvbf,
                                        query, Wq, bias, conv_b, qb2, ctx);

    // 2) fused GEMM + epilogue
    gemm_fused<<<4096, 256, 0, stream>>>(vbf, wvbf, qb2, last_attn, conv_w, fc_w, ep);

    // 3) fused softmax + context
    dim3 gc(32, 8);
    context_softmax<<<gc, 256, 0, stream>>>(ep, vbf, attn, ctx);
}